// Round 10
// baseline (354.479 us; speedup 1.0000x reference)
//
#include <hip/hip_runtime.h>
#include <hip/hip_bf16.h>
#include <stdint.h>

#define Bb 4
#define Ss 2048
#define Dd 1024
#define Hh 16
#define DK 64
#define BH 64
#define Mm 8192

typedef __attribute__((ext_vector_type(8))) _Float16 f16x8;
typedef __attribute__((ext_vector_type(2))) __fp16 fp16x2;
typedef __attribute__((ext_vector_type(4))) float f32x4;
typedef __attribute__((ext_vector_type(16))) float f32x16;
typedef __attribute__((ext_vector_type(2))) unsigned uint2v;

__device__ __forceinline__ void gload16(const _Float16* g, _Float16* lds) {
  __builtin_amdgcn_global_load_lds((const __attribute__((address_space(1))) unsigned int*)g,
                                   (__attribute__((address_space(3))) unsigned int*)lds, 16, 0, 0);
}

// pack two f32 -> u32 of 2 f16 (v_cvt_pkrtz_f16_f32, 1 inst)
__device__ __forceinline__ unsigned pk2u(float a, float b) {
  union { fp16x2 h; unsigned u; } x;
  x.h = __builtin_amdgcn_cvt_pkrtz(a, b);
  return x.u;
}

// ---------------- K0a: convert activations fp32 -> fp16 ----------------
__global__ __launch_bounds__(256) void cvt_act(const float* __restrict__ q,
                                               const float* __restrict__ k,
                                               const float* __restrict__ v,
                                               _Float16* __restrict__ xq,
                                               _Float16* __restrict__ xk,
                                               _Float16* __restrict__ xv) {
  const float* src = blockIdx.z == 0 ? q : (blockIdx.z == 1 ? k : v);
  _Float16* dst = blockIdx.z == 0 ? xq : (blockIdx.z == 1 ? xk : xv);
  int i = (blockIdx.x * 256 + threadIdx.x) * 8;
  float4 a = *(const float4*)(src + i);
  float4 b = *(const float4*)(src + i + 4);
  union { f16x8 v8; _Float16 h[8]; } o;
  o.h[0] = (_Float16)a.x; o.h[1] = (_Float16)a.y; o.h[2] = (_Float16)a.z; o.h[3] = (_Float16)a.w;
  o.h[4] = (_Float16)b.x; o.h[5] = (_Float16)b.y; o.h[6] = (_Float16)b.z; o.h[7] = (_Float16)b.w;
  *(f16x8*)(dst + i) = o.v8;
}

// ---------------- K0b: convert + transpose weights: Wt[n][k] = f16(W[k][n]) ----------------
// Q weights pre-scaled by log2(e) so attention scores land in the exp2 domain.
__global__ __launch_bounds__(256) void cvt_wt(const float* __restrict__ wq,
                                              const float* __restrict__ wk,
                                              const float* __restrict__ wv,
                                              _Float16* __restrict__ tq,
                                              _Float16* __restrict__ tk,
                                              _Float16* __restrict__ tv) {
  const float* w = blockIdx.z == 0 ? wq : (blockIdx.z == 1 ? wk : wv);
  _Float16* o = blockIdx.z == 0 ? tq : (blockIdx.z == 1 ? tk : tv);
  float wscale = blockIdx.z == 0 ? 1.4426950408889634f : 1.0f;
  __shared__ float tile[64][65];
  int k0 = blockIdx.x * 64;
  int n0 = blockIdx.y * 64;
  int t = threadIdx.x;
  int tr = t >> 4;
  int tc = (t & 15) * 4;
  for (int i = 0; i < 4; i++) {
    int r = i * 16 + tr;
    float4 val = *(const float4*)(w + (k0 + r) * Dd + n0 + tc);
    tile[r][tc + 0] = val.x; tile[r][tc + 1] = val.y;
    tile[r][tc + 2] = val.z; tile[r][tc + 3] = val.w;
  }
  __syncthreads();
  for (int i = 0; i < 2; i++) {
    int vdx = t + 256 * i;
    int rn = vdx >> 3;
    int c8 = (vdx & 7) * 8;
    union { f16x8 v8; _Float16 h[8]; } o2;
    for (int j = 0; j < 8; j++) o2.h[j] = (_Float16)(tile[c8 + j][rn] * wscale);
    *(f16x8*)(o + (n0 + rn) * Dd + k0 + c8) = o2.v8;
  }
}

// ---------------- K1: projection GEMM (m97 structure) ----------------
__global__ __launch_bounds__(256) void gemm_qkv(
    const _Float16* __restrict__ xq, const _Float16* __restrict__ xk,
    const _Float16* __restrict__ xv,
    const _Float16* __restrict__ wtq, const _Float16* __restrict__ wtk,
    const _Float16* __restrict__ wtv,
    const float* __restrict__ bq, const float* __restrict__ bk, const float* __restrict__ bv,
    _Float16* __restrict__ oq, _Float16* __restrict__ ok,
    _Float16* __restrict__ ov) {
  int z = blockIdx.z;
  const _Float16* A  = z == 0 ? xq  : (z == 1 ? xk  : xv);
  const _Float16* Bt = z == 0 ? wtq : (z == 1 ? wtk : wtv);
  const float* bias  = z == 0 ? bq  : (z == 1 ? bk  : bv);
  _Float16* out      = z == 0 ? oq  : (z == 1 ? ok  : ov);
  float bscale       = z == 0 ? 1.4426950408889634f : 1.0f;

  __shared__ _Float16 As[128 * 64];
  __shared__ _Float16 Bs[128 * 64];

  int tid = threadIdx.x;
  int w = tid >> 6;
  int l = tid & 63;
  int lr = l & 15, lk = l >> 4;
  int m0 = blockIdx.x * 128;
  int n0 = blockIdx.y * 128;
  int wr = (w >> 1) * 64;
  int wc = (w & 1) * 64;

  f32x4 acc[4][4] = {};

  for (int kt = 0; kt < Dd; kt += 64) {
    __syncthreads();
    for (int i = 0; i < 4; i++) {
      int fbase = i * 256 + w * 64;     // wave-uniform chunk base
      int f = fbase + l;
      int r = f >> 3, c = (f & 7) * 8;
      gload16(A + (m0 + r) * Dd + kt + c, &As[fbase * 8]);
      gload16(Bt + (n0 + r) * Dd + kt + c, &Bs[fbase * 8]);
    }
    __syncthreads();
    for (int kh = 0; kh < 2; kh++) {
      f16x8 af[4], bfr[4];
      for (int mi = 0; mi < 4; mi++)
        af[mi] = *(const f16x8*)&As[(wr + mi * 16 + lr) * 64 + kh * 32 + lk * 8];
      for (int ni = 0; ni < 4; ni++)
        bfr[ni] = *(const f16x8*)&Bs[(wc + ni * 16 + lr) * 64 + kh * 32 + lk * 8];
      for (int mi = 0; mi < 4; mi++)
        for (int ni = 0; ni < 4; ni++)
          acc[mi][ni] = __builtin_amdgcn_mfma_f32_16x16x32_f16(af[mi], bfr[ni], acc[mi][ni], 0, 0, 0);
    }
  }

  for (int mi = 0; mi < 4; mi++) {
    for (int ni = 0; ni < 4; ni++) {
      int n = n0 + wc + ni * 16 + lr;
      float bval = bias[n] * bscale;
      int h = n >> 6, dk = n & 63;
      for (int j = 0; j < 4; j++) {
        int m = m0 + wr + mi * 16 + lk * 4 + j;
        int b = m >> 11, s = m & 2047;
        out[((b * Hh + h) * Ss + s) * DK + dk] = (_Float16)(acc[mi][ni][j] + bval);
      }
    }
  }
}

// ---------------- K2: transpose V: [bh][s][dk] -> [bh][dk][s] ----------------
__global__ __launch_bounds__(256) void transpose_v(const unsigned short* __restrict__ vin,
                                                   unsigned short* __restrict__ vout) {
  __shared__ unsigned short t[64][80];
  typedef __attribute__((ext_vector_type(8))) short s16x8;
  int bh = blockIdx.y;
  int s0 = blockIdx.x * 64;
  int tid = threadIdx.x;
  const unsigned short* vp = vin + bh * (Ss * DK);
  for (int i = 0; i < 2; i++) {
    int v = tid + 256 * i;
    int r = v >> 3, c8 = (v & 7) * 8;
    s16x8 val = *(const s16x8*)(vp + (s0 + r) * DK + c8);
    *(s16x8*)&t[r][c8] = val;
  }
  __syncthreads();
  unsigned short* op = vout + bh * (DK * Ss);
  for (int i = 0; i < 2; i++) {
    int v = tid + 256 * i;
    int rn = v >> 3;
    int c8 = (v & 7) * 8;
    union { s16x8 v8; unsigned short u[8]; } o2;
    for (int j = 0; j < 8; j++) o2.u[j] = t[c8 + j][rn];
    *(s16x8*)(op + rn * Ss + s0 + c8) = o2.v8;
  }
}

// ---------------- K3: flash attention — reg-staged pipeline, compiler-managed waits ----------------
// Q,K: [bh][s][64] f16 (Q pre-scaled by log2e); Vt: [bh][64][s] f16; out = ctx + query.
// Per-wave independent (no LDS, no barriers): 32 q-rows/wave, kv-tile 32, unrolled x2
// (named A/B register sets, rule #20). Per half-tile: QK(4 mfma_32x32x16) -> PLAIN C++
// prefetch loads for V(t+1)/K(t+2) -> sched_barrier(0) pins them (prevents the r5/r6
// sink-to-use) -> softmax (exp2 domain) covers latency -> PV(4 mfma). Waitcnts are
// compiler-inserted with exact counts (no hand-counted vmcnt — the r9 failure mode).
__global__ __launch_bounds__(256) void attn(const _Float16* __restrict__ Qb,
                                            const _Float16* __restrict__ Kb,
                                            const _Float16* __restrict__ Vt,
                                            const float* __restrict__ query,
                                            float* __restrict__ outp) {
  int tid = threadIdx.x;
  int w = tid >> 6;
  int l31 = tid & 31;
  int hi = (tid >> 5) & 1;
  int bh = blockIdx.x;                 // flat%8 = bh%8: all q-blocks of a head share an XCD
  int q0 = blockIdx.y * 128 + w * 32;
  const _Float16* Qp = Qb + bh * (Ss * DK);
  const _Float16* Kp = Kb + bh * (Ss * DK);
  const _Float16* Vp = Vt + bh * (DK * Ss);

  // Q as B-operand: col=q=q0+l31, k=dk=s*16+hi*8+i
  f16x8 qf[4];
#pragma unroll
  for (int s = 0; s < 4; s++)
    qf[s] = *(const f16x8*)(Qp + (q0 + l31) * DK + s * 16 + hi * 8);

  f32x16 o0 = {}, o1 = {};    // ctx^T: row d=dg*32+(r&3)+8*(r>>2)+4*hi, col q=l31
  float mrun = -1e30f, lrun = 0.f;

  const _Float16* krow = Kp + l31 * DK + hi * 8;   // + kv*DK walks kv
  const _Float16* vrow = Vp + l31 * Ss + hi * 8;   // + kv walks kv; +32*Ss is d+32

  f16x8 kA[4], kB[4], vA[4], vB[4];

  // prologue: K0 -> kA, V0 -> vA, K1 -> kB; pin issue here
#pragma unroll
  for (int s = 0; s < 4; s++) kA[s] = *(const f16x8*)(krow + s * 16);
  vA[0] = *(const f16x8*)(vrow);
  vA[1] = *(const f16x8*)(vrow + 32 * Ss);
  vA[2] = *(const f16x8*)(vrow + 16);
  vA[3] = *(const f16x8*)(vrow + 16 + 32 * Ss);
#pragma unroll
  for (int s = 0; s < 4; s++) kB[s] = *(const f16x8*)(krow + 32 * DK + s * 16);
  __builtin_amdgcn_sched_barrier(0);

  // KR: K regs for this half (ready). VR: V regs for this half (loaded one half ago).
  // VD: V reg set to prefetch kv=KVV into. KD: K reg set to prefetch kv=KVK into.
#define HALF(KR, VR, VD, KD, KVV, KVK)                                          \
  {                                                                             \
    f32x16 sc = {};                                                             \
    __builtin_amdgcn_s_setprio(1);                                              \
    _Pragma("unroll")                                                           \
    for (int s = 0; s < 4; s++)                                                 \
      sc = __builtin_amdgcn_mfma_f32_32x32x16_f16(KR[s], qf[s], sc, 0, 0, 0);   \
    __builtin_amdgcn_s_setprio(0);                                              \
    { const _Float16* vp_ = vrow + (KVV);                                       \
      VD[0] = *(const f16x8*)(vp_);                                             \
      VD[1] = *(const f16x8*)(vp_ + 32 * Ss);                                   \
      VD[2] = *(const f16x8*)(vp_ + 16);                                        \
      VD[3] = *(const f16x8*)(vp_ + 16 + 32 * Ss); }                            \
    { const _Float16* kp_ = krow + (size_t)(KVK) * DK;                          \
      KD[0] = *(const f16x8*)(kp_);                                             \
      KD[1] = *(const f16x8*)(kp_ + 16);                                        \
      KD[2] = *(const f16x8*)(kp_ + 32);                                        \
      KD[3] = *(const f16x8*)(kp_ + 48); }                                      \
    __builtin_amdgcn_sched_barrier(0);  /* pin prefetch issue before softmax */ \
    float m8[8];                                                                \
    _Pragma("unroll")                                                           \
    for (int r = 0; r < 8; r++) m8[r] = fmaxf(sc[r], sc[r + 8]);                \
    _Pragma("unroll")                                                           \
    for (int d = 4; d >= 1; d >>= 1)                                            \
      for (int r = 0; r < 4; r++) if (r < d) m8[r] = fmaxf(m8[r], m8[r + d]);   \
    float pm = fmaxf(m8[0], __shfl_xor(m8[0], 32));                             \
    if (!__all(pm - mrun <= 8.f)) {   /* defer-max, log2 units (P <= 256) */    \
      float mn = fmaxf(mrun, pm);                                               \
      float rs_ = exp2f(mrun - mn);                                             \
      mrun = mn; lrun *= rs_;                                                   \
      _Pragma("unroll")                                                         \
      for (int r = 0; r < 16; r++) { o0[r] *= rs_; o1[r] *= rs_; }              \
    }                                                                           \
    _Pragma("unroll")                                                           \
    for (int r = 0; r < 16; r++) sc[r] = exp2f(sc[r] - mrun);                   \
    float s8[8];                                                                \
    _Pragma("unroll")                                                           \
    for (int r = 0; r < 8; r++) s8[r] = sc[r] + sc[r + 8];                      \
    _Pragma("unroll")                                                           \
    for (int d = 4; d >= 1; d >>= 1)                                            \
      for (int r = 0; r < 4; r++) if (r < d) s8[r] += s8[r + d];                \
    lrun += s8[0] + __shfl_xor(s8[0], 32);                                      \
    __builtin_amdgcn_s_setprio(1);                                              \
    {                                                                           \
      unsigned a0 = pk2u(sc[0], sc[1]), a1 = pk2u(sc[2], sc[3]);                \
      unsigned b0 = pk2u(sc[4], sc[5]), b1 = pk2u(sc[6], sc[7]);                \
      uint2v r0 = __builtin_amdgcn_permlane32_swap(a0, b0, false, false);       \
      uint2v r1 = __builtin_amdgcn_permlane32_swap(a1, b1, false, false);       \
      union { unsigned u[4]; f16x8 v; } pf;                                     \
      pf.u[0] = r0[0]; pf.u[1] = r1[0]; pf.u[2] = r0[1]; pf.u[3] = r1[1];       \
      o0 = __builtin_amdgcn_mfma_f32_32x32x16_f16(VR[0], pf.v, o0, 0, 0, 0);    \
      o1 = __builtin_amdgcn_mfma_f32_32x32x16_f16(VR[1], pf.v, o1, 0, 0, 0);    \
    }                                                                           \
    {                                                                           \
      unsigned a0 = pk2u(sc[8], sc[9]), a1 = pk2u(sc[10], sc[11]);              \
      unsigned b0 = pk2u(sc[12], sc[13]), b1 = pk2u(sc[14], sc[15]);            \
      uint2v r0 = __builtin_amdgcn_permlane32_swap(a0, b0, false, false);       \
      uint2v r1 = __builtin_amdgcn_permlane32_swap(a1, b1, false, false);       \
      union { unsigned u[4]; f16x8 v; } pf;                                     \
      pf.u[0] = r0[0]; pf.u[1] = r1[0]; pf.u[2] = r0[1]; pf.u[3] = r1[1];       \
      o0 = __builtin_amdgcn_mfma_f32_32x32x16_f16(VR[2], pf.v, o0, 0, 0, 0);    \
      o1 = __builtin_amdgcn_mfma_f32_32x32x16_f16(VR[3], pf.v, o1, 0, 0, 0);    \
    }                                                                           \
    __builtin_amdgcn_s_setprio(0);                                              \
  }

  for (int it = 0; it < Ss / 64; ++it) {
    int kv0 = it * 64;
    int nx  = kv0 + 64 < Ss ? kv0 + 64 : 0;    // clamp tail prefetch in-bounds (dead)
    int nx2 = kv0 + 96 < Ss ? kv0 + 96 : 0;
    HALF(kA, vA, vB, kA, kv0 + 32, nx)
    HALF(kB, vB, vA, kB, nx, nx2)
  }
#undef HALF

  // ---- epilogue: lane q=q0+l31; d = dg*32 + rq*8 + hi*4 + j ----
  int b = bh >> 4, h = bh & 15;
  float inv = 1.f / lrun;
  int base = (b * Ss + q0 + l31) * Dd + h * 64;
#pragma unroll
  for (int rq = 0; rq < 4; rq++) {
    int d0 = rq * 8 + hi * 4;
    float4 qv0 = *(const float4*)(query + base + d0);
    float4 ov0;
    ov0.x = o0[rq * 4 + 0] * inv + qv0.x;
    ov0.y = o0[rq * 4 + 1] * inv + qv0.y;
    ov0.z = o0[rq * 4 + 2] * inv + qv0.z;
    ov0.w = o0[rq * 4 + 3] * inv + qv0.w;
    *(float4*)(outp + base + d0) = ov0;
    float4 qv1 = *(const float4*)(query + base + 32 + d0);
    float4 ov1;
    ov1.x = o1[rq * 4 + 0] * inv + qv1.x;
    ov1.y = o1[rq * 4 + 1] * inv + qv1.y;
    ov1.z = o1[rq * 4 + 2] * inv + qv1.z;
    ov1.w = o1[rq * 4 + 3] * inv + qv1.w;
    *(float4*)(outp + base + 32 + d0) = ov1;
  }
}

extern "C" void kernel_launch(void* const* d_in, const int* in_sizes, int n_in,
                              void* d_out, int out_size, void* d_ws, size_t ws_size,
                              hipStream_t stream) {
  const float* query = (const float*)d_in[0];
  const float* key   = (const float*)d_in[1];
  const float* value = (const float*)d_in[2];
  const float* Wq = (const float*)d_in[3];
  const float* bq = (const float*)d_in[4];
  const float* Wk = (const float*)d_in[5];
  const float* bk = (const float*)d_in[6];
  const float* Wv = (const float*)d_in[7];
  const float* bv = (const float*)d_in[8];
  float* out = (float*)d_out;

  _Float16* ws = (_Float16*)d_ws;
  const size_t ACT = (size_t)Mm * Dd;
  const size_t WSZ = (size_t)Dd * Dd;
  _Float16* Xq   = ws;
  _Float16* Xk   = Xq + ACT;
  _Float16* Xv   = Xk + ACT;
  _Float16* Wtq  = Xv + ACT;
  _Float16* Wtk  = Wtq + WSZ;
  _Float16* Wtv  = Wtk + WSZ;
  _Float16* Qb   = Wtv + WSZ;
  _Float16* Kb   = Qb + ACT;
  _Float16* Vtmp = Kb + ACT;
  _Float16* VtT  = Vtmp + ACT;

  cvt_act<<<dim3(4096, 1, 3), dim3(256), 0, stream>>>(query, key, value, Xq, Xk, Xv);
  cvt_wt<<<dim3(16, 16, 3), dim3(256), 0, stream>>>(Wq, Wk, Wv, Wtq, Wtk, Wtv);
  gemm_qkv<<<dim3(64, 8, 3), dim3(256), 0, stream>>>(Xq, Xk, Xv, Wtq, Wtk, Wtv,
                                                     bq, bk, bv, Qb, Kb, Vtmp);
  transpose_v<<<dim3(32, 64), dim3(256), 0, stream>>>((const unsigned short*)Vtmp,
                                                      (unsigned short*)VtT);
  attn<<<dim3(64, 16), dim3(256), 0, stream>>>(Qb, Kb, VtT, query, out);
}

// Round 11
// 250.401 us; speedup vs baseline: 1.4156x; 1.4156x over previous
//
#include <hip/hip_runtime.h>
#include <hip/hip_bf16.h>
#include <stdint.h>

#define Bb 4
#define Ss 2048
#define Dd 1024
#define Hh 16
#define DK 64
#define BH 64
#define Mm 8192
#define KVT 64

typedef __attribute__((ext_vector_type(8))) _Float16 f16x8;
typedef __attribute__((ext_vector_type(4))) _Float16 f16x4;
typedef __attribute__((ext_vector_type(2))) __fp16 fp16x2;
typedef __attribute__((ext_vector_type(4))) float f32x4;
typedef __attribute__((ext_vector_type(16))) float f32x16;
typedef __attribute__((ext_vector_type(2))) unsigned uint2v;

__device__ __forceinline__ void gload16(const _Float16* g, _Float16* lds) {
  __builtin_amdgcn_global_load_lds((const __attribute__((address_space(1))) unsigned int*)g,
                                   (__attribute__((address_space(3))) unsigned int*)lds, 16, 0, 0);
}

// pack two f32 -> u32 of 2 f16 (v_cvt_pkrtz_f16_f32, 1 inst; validated r10)
__device__ __forceinline__ unsigned pk2u(float a, float b) {
  union { fp16x2 h; unsigned u; } x;
  x.h = __builtin_amdgcn_cvt_pkrtz(a, b);
  return x.u;
}

// ---------------- K0a: convert activations fp32 -> fp16 ----------------
__global__ __launch_bounds__(256) void cvt_act(const float* __restrict__ q,
                                               const float* __restrict__ k,
                                               const float* __restrict__ v,
                                               _Float16* __restrict__ xq,
                                               _Float16* __restrict__ xk,
                                               _Float16* __restrict__ xv) {
  const float* src = blockIdx.z == 0 ? q : (blockIdx.z == 1 ? k : v);
  _Float16* dst = blockIdx.z == 0 ? xq : (blockIdx.z == 1 ? xk : xv);
  int i = (blockIdx.x * 256 + threadIdx.x) * 8;
  float4 a = *(const float4*)(src + i);
  float4 b = *(const float4*)(src + i + 4);
  union { f16x8 v8; _Float16 h[8]; } o;
  o.h[0] = (_Float16)a.x; o.h[1] = (_Float16)a.y; o.h[2] = (_Float16)a.z; o.h[3] = (_Float16)a.w;
  o.h[4] = (_Float16)b.x; o.h[5] = (_Float16)b.y; o.h[6] = (_Float16)b.z; o.h[7] = (_Float16)b.w;
  *(f16x8*)(dst + i) = o.v8;
}

// ---------------- K0b: convert + transpose weights: Wt[n][k] = f16(W[k][n]) ----------------
// Q weights pre-scaled by log2(e): attention scores land in the exp2 domain (saves a mul/exp).
__global__ __launch_bounds__(256) void cvt_wt(const float* __restrict__ wq,
                                              const float* __restrict__ wk,
                                              const float* __restrict__ wv,
                                              _Float16* __restrict__ tq,
                                              _Float16* __restrict__ tk,
                                              _Float16* __restrict__ tv) {
  const float* w = blockIdx.z == 0 ? wq : (blockIdx.z == 1 ? wk : wv);
  _Float16* o = blockIdx.z == 0 ? tq : (blockIdx.z == 1 ? tk : tv);
  float wscale = blockIdx.z == 0 ? 1.4426950408889634f : 1.0f;
  __shared__ float tile[64][65];
  int k0 = blockIdx.x * 64;
  int n0 = blockIdx.y * 64;
  int t = threadIdx.x;
  int tr = t >> 4;
  int tc = (t & 15) * 4;
  for (int i = 0; i < 4; i++) {
    int r = i * 16 + tr;
    float4 val = *(const float4*)(w + (k0 + r) * Dd + n0 + tc);
    tile[r][tc + 0] = val.x; tile[r][tc + 1] = val.y;
    tile[r][tc + 2] = val.z; tile[r][tc + 3] = val.w;
  }
  __syncthreads();
  for (int i = 0; i < 2; i++) {
    int vdx = t + 256 * i;
    int rn = vdx >> 3;
    int c8 = (vdx & 7) * 8;
    union { f16x8 v8; _Float16 h[8]; } o2;
    for (int j = 0; j < 8; j++) o2.h[j] = (_Float16)(tile[c8 + j][rn] * wscale);
    *(f16x8*)(o + (n0 + rn) * Dd + k0 + c8) = o2.v8;
  }
}

// ---------------- K1: projection GEMM (m97 structure) ----------------
// Q,K outputs in [bh][s][dk]; V output written TRANSPOSED [bh][dk][s] (replaces transpose_v).
__global__ __launch_bounds__(256) void gemm_qkv(
    const _Float16* __restrict__ xq, const _Float16* __restrict__ xk,
    const _Float16* __restrict__ xv,
    const _Float16* __restrict__ wtq, const _Float16* __restrict__ wtk,
    const _Float16* __restrict__ wtv,
    const float* __restrict__ bq, const float* __restrict__ bk, const float* __restrict__ bv,
    _Float16* __restrict__ oq, _Float16* __restrict__ ok,
    _Float16* __restrict__ ov) {
  int z = blockIdx.z;
  const _Float16* A  = z == 0 ? xq  : (z == 1 ? xk  : xv);
  const _Float16* Bt = z == 0 ? wtq : (z == 1 ? wtk : wtv);
  const float* bias  = z == 0 ? bq  : (z == 1 ? bk  : bv);
  _Float16* out      = z == 0 ? oq  : (z == 1 ? ok  : ov);
  float bscale       = z == 0 ? 1.4426950408889634f : 1.0f;

  __shared__ _Float16 As[128 * 64];
  __shared__ _Float16 Bs[128 * 64];

  int tid = threadIdx.x;
  int w = tid >> 6;
  int l = tid & 63;
  int lr = l & 15, lk = l >> 4;
  int m0 = blockIdx.x * 128;
  int n0 = blockIdx.y * 128;
  int wr = (w >> 1) * 64;
  int wc = (w & 1) * 64;

  f32x4 acc[4][4] = {};

  for (int kt = 0; kt < Dd; kt += 64) {
    __syncthreads();
    for (int i = 0; i < 4; i++) {
      int fbase = i * 256 + w * 64;     // wave-uniform chunk base
      int f = fbase + l;
      int r = f >> 3, c = (f & 7) * 8;
      gload16(A + (m0 + r) * Dd + kt + c, &As[fbase * 8]);
      gload16(Bt + (n0 + r) * Dd + kt + c, &Bs[fbase * 8]);
    }
    __syncthreads();
    for (int kh = 0; kh < 2; kh++) {
      f16x8 af[4], bfr[4];
      for (int mi = 0; mi < 4; mi++)
        af[mi] = *(const f16x8*)&As[(wr + mi * 16 + lr) * 64 + kh * 32 + lk * 8];
      for (int ni = 0; ni < 4; ni++)
        bfr[ni] = *(const f16x8*)&Bs[(wc + ni * 16 + lr) * 64 + kh * 32 + lk * 8];
      for (int mi = 0; mi < 4; mi++)
        for (int ni = 0; ni < 4; ni++)
          acc[mi][ni] = __builtin_amdgcn_mfma_f32_16x16x32_f16(af[mi], bfr[ni], acc[mi][ni], 0, 0, 0);
    }
  }

  if (z == 2) {
    // V^T epilogue: lane holds 4 consecutive s for fixed dk -> one aligned 8B store
    for (int mi = 0; mi < 4; mi++) {
      for (int ni = 0; ni < 4; ni++) {
        int n = n0 + wc + ni * 16 + lr;
        float bval = bias[n];
        int h = n >> 6, dk = n & 63;
        int m = m0 + wr + mi * 16 + lk * 4;
        int b = m >> 11, s = m & 2047;
        f16x4 o4;
        for (int j = 0; j < 4; j++) o4[j] = (_Float16)(acc[mi][ni][j] + bval);
        *(f16x4*)(out + ((size_t)((b * Hh + h) * DK + dk) * Ss + s)) = o4;
      }
    }
  } else {
    for (int mi = 0; mi < 4; mi++) {
      for (int ni = 0; ni < 4; ni++) {
        int n = n0 + wc + ni * 16 + lr;
        float bval = bias[n] * bscale;
        int h = n >> 6, dk = n & 63;
        for (int j = 0; j < 4; j++) {
          int m = m0 + wr + mi * 16 + lk * 4 + j;
          int b = m >> 11, s = m & 2047;
          out[((b * Hh + h) * Ss + s) * DK + dk] = (_Float16)(acc[mi][ni][j] + bval);
        }
      }
    }
  }
}

// ---------------- K3: flash attention, 32x32x16, LDS double-buffered K/V (r7 skeleton) ----------------
// Q,K: [bh][s][64] f16 (Q pre-scaled by log2e); Vt: [bh][64][s] f16; out fp32 = ctx + query.
// 1024 blocks x 4 waves. Block = 128 q-rows (32/wave), kv-tile 64, double-buffered LDS via
// global_load_lds DMA (the only staging mechanism this compiler reliably pipelines — r5/6/8/9/10).
// XOR-swizzled K/V tiles (inverse-swizzled global source + swizzled reads, rule #21).
// Softmax: exp2 domain, lane-local + 1 max-shfl/tile; lrun lane-partial (reduced once in epilogue).
// P in-register via cvt_pkrtz + permlane32_swap; setprio(1) around MFMA clusters (T5).
__global__ __launch_bounds__(256) void attn(const _Float16* __restrict__ Qb,
                                            const _Float16* __restrict__ Kb,
                                            const _Float16* __restrict__ Vt,
                                            const float* __restrict__ query,
                                            float* __restrict__ outp) {
  __shared__ _Float16 Kl[2][KVT * 64];
  __shared__ _Float16 Vl[2][KVT * 64];

  int tid = threadIdx.x;
  int w = tid >> 6, l = tid & 63;
  int l31 = l & 31, hi = l >> 5;
  int bh = blockIdx.x;
  int q0 = blockIdx.y * 128 + w * 32;
  const _Float16* Qp = Qb + bh * (Ss * DK);
  const _Float16* Kp = Kb + bh * (Ss * DK);
  const _Float16* Vp = Vt + bh * (DK * Ss);

  // staging: lane l -> row base+(l>>3), LDS slot l&7; global slot = (l&7)^(row&7)
  int srow = l >> 3;
  int sslot = (l & 7) ^ (srow & 7);
  int w16 = w * 16;
  const _Float16* ksrc0 = Kp + (w16 + srow) * DK + sslot * 8;
  const _Float16* ksrc1 = Kp + (w16 + 8 + srow) * DK + sslot * 8;
  const _Float16* vsrc0 = Vp + (w16 + srow) * Ss + sslot * 8;
  const _Float16* vsrc1 = Vp + (w16 + 8 + srow) * Ss + sslot * 8;

#define STAGE(KV0, BUF)                                                   \
  {                                                                       \
    gload16(ksrc0 + (KV0) * DK, &Kl[BUF][w16 * 64]);                      \
    gload16(ksrc1 + (KV0) * DK, &Kl[BUF][(w16 + 8) * 64]);                \
    gload16(vsrc0 + (KV0), &Vl[BUF][w16 * 64]);                           \
    gload16(vsrc1 + (KV0), &Vl[BUF][(w16 + 8) * 64]);                     \
  }

  // Q as B-operand: col=q=q0+l31, k=dk=s*16+hi*8+i
  f16x8 qf[4];
#pragma unroll
  for (int s = 0; s < 4; s++)
    qf[s] = *(const f16x8*)(Qp + (q0 + l31) * DK + s * 16 + hi * 8);

  f32x16 o0 = {}, o1 = {};    // ctx^T: row d=dg*32+(r&3)+8*(r>>2)+4*hi, col q=l31
  float mrun = -1e30f, lrun = 0.f;   // lrun is LANE-PARTIAL (this half's sum)

  // swizzled LDS read slots: slot = ((s*2+hi) ^ (row&7)), row&7 == l31&7 for our reads
  int kv7 = l31 & 7;
  int rslot[4];
#pragma unroll
  for (int s = 0; s < 4; s++) rslot[s] = ((s * 2 + hi) ^ kv7) * 8;

  STAGE(0, 0)
  __syncthreads();

  int cur = 0;
  for (int kv0 = 0; kv0 < Ss; kv0 += KVT) {
    // issue next-tile staging (DMA completes under this tile's compute)
    if (kv0 + KVT < Ss) STAGE(kv0 + KVT, cur ^ 1)

    // ---- QK^T (swapped): A=K rows kv from LDS, B=qf ----
    const _Float16* Kc = &Kl[cur][0];
    f32x16 s0 = {}, s1 = {};
    __builtin_amdgcn_s_setprio(1);
#pragma unroll
    for (int s = 0; s < 4; s++) {
      f16x8 ka = *(const f16x8*)&Kc[l31 * 64 + rslot[s]];
      s0 = __builtin_amdgcn_mfma_f32_32x32x16_f16(ka, qf[s], s0, 0, 0, 0);
    }
#pragma unroll
    for (int s = 0; s < 4; s++) {
      f16x8 kb = *(const f16x8*)&Kc[(32 + l31) * 64 + rslot[s]];
      s1 = __builtin_amdgcn_mfma_f32_32x32x16_f16(kb, qf[s], s1, 0, 0, 0);
    }
    __builtin_amdgcn_s_setprio(0);

    // ---- lane-local online softmax (exp2 domain) ----
    float m8[8];
#pragma unroll
    for (int r = 0; r < 8; r++)
      m8[r] = fmaxf(fmaxf(s0[r], s0[r + 8]), fmaxf(s1[r], s1[r + 8]));  // v_max3-fusable
#pragma unroll
    for (int d = 4; d >= 1; d >>= 1)
#pragma unroll
      for (int r = 0; r < 4; r++) if (r < d) m8[r] = fmaxf(m8[r], m8[r + d]);
    float pm = fmaxf(m8[0], __shfl_xor(m8[0], 32));

    if (!__all(pm - mrun <= 8.f)) {        // defer-max (T13), log2 units: P <= 2^8
      float mn = fmaxf(mrun, pm);
      float sc_ = exp2f(mrun - mn);
      mrun = mn;
      lrun *= sc_;
#pragma unroll
      for (int r = 0; r < 16; r++) { o0[r] *= sc_; o1[r] *= sc_; }
    }
#pragma unroll
    for (int r = 0; r < 16; r++) {
      s0[r] = exp2f(s0[r] - mrun);
      s1[r] = exp2f(s1[r] - mrun);
    }
    float s8[8];
#pragma unroll
    for (int r = 0; r < 8; r++) s8[r] = (s0[r] + s0[r + 8]) + (s1[r] + s1[r + 8]);
#pragma unroll
    for (int d = 4; d >= 1; d >>= 1)
#pragma unroll
      for (int r = 0; r < 4; r++) if (r < d) s8[r] += s8[r + d];
    lrun += s8[0];    // lane-partial; cross-half reduce deferred to epilogue

    // ---- pack P + permlane32_swap + PV MFMA (V from LDS, swizzled) ----
    const _Float16* Vc = &Vl[cur][0];
    __builtin_amdgcn_s_setprio(1);
#define PVSTEP(SRC, OFF, KST)                                                   \
    {                                                                           \
      unsigned a0 = pk2u(SRC[(OFF) + 0], SRC[(OFF) + 1]);                       \
      unsigned a1 = pk2u(SRC[(OFF) + 2], SRC[(OFF) + 3]);                       \
      unsigned b0 = pk2u(SRC[(OFF) + 4], SRC[(OFF) + 5]);                       \
      unsigned b1 = pk2u(SRC[(OFF) + 6], SRC[(OFF) + 7]);                       \
      uint2v r0 = __builtin_amdgcn_permlane32_swap(a0, b0, false, false);       \
      uint2v r1 = __builtin_amdgcn_permlane32_swap(a1, b1, false, false);       \
      union { unsigned u[4]; f16x8 v; } pf;                                     \
      pf.u[0] = r0[0]; pf.u[1] = r1[0]; pf.u[2] = r0[1]; pf.u[3] = r1[1];       \
      f16x8 v0 = *(const f16x8*)&Vc[l31 * 64 + rslot[KST]];                     \
      f16x8 v1 = *(const f16x8*)&Vc[(32 + l31) * 64 + rslot[KST]];              \
      o0 = __builtin_amdgcn_mfma_f32_32x32x16_f16(v0, pf.v, o0, 0, 0, 0);       \
      o1 = __builtin_amdgcn_mfma_f32_32x32x16_f16(v1, pf.v, o1, 0, 0, 0);       \
    }
    PVSTEP(s0, 0, 0)
    PVSTEP(s0, 8, 1)
    PVSTEP(s1, 0, 2)
    PVSTEP(s1, 8, 3)
#undef PVSTEP
    __builtin_amdgcn_s_setprio(0);

    __syncthreads();   // reads of buf[cur] done; staging of buf[cur^1] drained
    cur ^= 1;
  }

  // ---- epilogue: reduce lane-partial lrun, normalize, add residual ----
  lrun += __shfl_xor(lrun, 32);
  int b = bh >> 4, h = bh & 15;
  float inv = 1.f / lrun;
  int base = (b * Ss + q0 + l31) * Dd + h * 64;
#pragma unroll
  for (int rq = 0; rq < 4; rq++) {
    int d0 = rq * 8 + hi * 4;
    float4 qv0 = *(const float4*)(query + base + d0);
    float4 ov0;
    ov0.x = o0[rq * 4 + 0] * inv + qv0.x;
    ov0.y = o0[rq * 4 + 1] * inv + qv0.y;
    ov0.z = o0[rq * 4 + 2] * inv + qv0.z;
    ov0.w = o0[rq * 4 + 3] * inv + qv0.w;
    *(float4*)(outp + base + d0) = ov0;
    float4 qv1 = *(const float4*)(query + base + 32 + d0);
    float4 ov1;
    ov1.x = o1[rq * 4 + 0] * inv + qv1.x;
    ov1.y = o1[rq * 4 + 1] * inv + qv1.y;
    ov1.z = o1[rq * 4 + 2] * inv + qv1.z;
    ov1.w = o1[rq * 4 + 3] * inv + qv1.w;
    *(float4*)(outp + base + 32 + d0) = ov1;
  }
#undef STAGE
}

extern "C" void kernel_launch(void* const* d_in, const int* in_sizes, int n_in,
                              void* d_out, int out_size, void* d_ws, size_t ws_size,
                              hipStream_t stream) {
  const float* query = (const float*)d_in[0];
  const float* key   = (const float*)d_in[1];
  const float* value = (const float*)d_in[2];
  const float* Wq = (const float*)d_in[3];
  const float* bq = (const float*)d_in[4];
  const float* Wk = (const float*)d_in[5];
  const float* bk = (const float*)d_in[6];
  const float* Wv = (const float*)d_in[7];
  const float* bv = (const float*)d_in[8];
  float* out = (float*)d_out;

  _Float16* ws = (_Float16*)d_ws;
  const size_t ACT = (size_t)Mm * Dd;
  const size_t WSZ = (size_t)Dd * Dd;
  _Float16* Xq   = ws;
  _Float16* Xk   = Xq + ACT;
  _Float16* Xv   = Xk + ACT;
  _Float16* Wtq  = Xv + ACT;
  _Float16* Wtk  = Wtq + WSZ;
  _Float16* Wtv  = Wtk + WSZ;
  _Float16* Qb   = Wtv + WSZ;
  _Float16* Kb   = Qb + ACT;
  _Float16* VtT  = Kb + ACT;   // gemm writes V^T [bh][dk][s] here directly

  cvt_act<<<dim3(4096, 1, 3), dim3(256), 0, stream>>>(query, key, value, Xq, Xk, Xv);
  cvt_wt<<<dim3(16, 16, 3), dim3(256), 0, stream>>>(Wq, Wk, Wv, Wtq, Wtk, Wtv);
  gemm_qkv<<<dim3(64, 8, 3), dim3(256), 0, stream>>>(Xq, Xk, Xv, Wtq, Wtk, Wtv,
                                                     bq, bk, bv, Qb, Kb, VtT);
  attn<<<dim3(64, 16), dim3(256), 0, stream>>>(Qb, Kb, VtT, query, out);
}

// Round 14
// 221.151 us; speedup vs baseline: 1.6029x; 1.1323x over previous
//
#include <hip/hip_runtime.h>
#include <hip/hip_bf16.h>
#include <stdint.h>

#define Bb 4
#define Ss 2048
#define Dd 1024
#define Hh 16
#define DK 64
#define BH 64
#define Mm 8192
#define KVT 64

typedef __attribute__((ext_vector_type(8))) _Float16 f16x8;
typedef __attribute__((ext_vector_type(4))) _Float16 f16x4;
typedef __attribute__((ext_vector_type(2))) __fp16 fp16x2;
typedef __attribute__((ext_vector_type(4))) float f32x4;
typedef __attribute__((ext_vector_type(16))) float f32x16;
typedef __attribute__((ext_vector_type(2))) unsigned uint2v;

__device__ __forceinline__ void gload16(const _Float16* g, _Float16* lds) {
  __builtin_amdgcn_global_load_lds((const __attribute__((address_space(1))) unsigned int*)g,
                                   (__attribute__((address_space(3))) unsigned int*)lds, 16, 0, 0);
}

// single v_exp_f32 (2^x). exp2f() is the libm path (~5-8 insts) — the r11 regression.
#if __has_builtin(__builtin_amdgcn_exp2f)
__device__ __forceinline__ float ex2(float x) { return __builtin_amdgcn_exp2f(x); }
#else
__device__ __forceinline__ float ex2(float x) {
  float r; asm("v_exp_f32 %0, %1" : "=v"(r) : "v"(x)); return r;
}
#endif

// pack two f32 -> u32 of 2 f16 (v_cvt_pkrtz_f16_f32, 1 inst; validated r10)
__device__ __forceinline__ unsigned pk2u(float a, float b) {
  union { fp16x2 h; unsigned u; } x;
  x.h = __builtin_amdgcn_cvt_pkrtz(a, b);
  return x.u;
}

// ---------------- K0a: convert activations fp32 -> fp16 ----------------
__global__ __launch_bounds__(256) void cvt_act(const float* __restrict__ q,
                                               const float* __restrict__ k,
                                               const float* __restrict__ v,
                                               _Float16* __restrict__ xq,
                                               _Float16* __restrict__ xk,
                                               _Float16* __restrict__ xv) {
  const float* src = blockIdx.z == 0 ? q : (blockIdx.z == 1 ? k : v);
  _Float16* dst = blockIdx.z == 0 ? xq : (blockIdx.z == 1 ? xk : xv);
  int i = (blockIdx.x * 256 + threadIdx.x) * 8;
  float4 a = *(const float4*)(src + i);
  float4 b = *(const float4*)(src + i + 4);
  union { f16x8 v8; _Float16 h[8]; } o;
  o.h[0] = (_Float16)a.x; o.h[1] = (_Float16)a.y; o.h[2] = (_Float16)a.z; o.h[3] = (_Float16)a.w;
  o.h[4] = (_Float16)b.x; o.h[5] = (_Float16)b.y; o.h[6] = (_Float16)b.z; o.h[7] = (_Float16)b.w;
  *(f16x8*)(dst + i) = o.v8;
}

// ---------------- K0b: convert + transpose weights: Wt[n][k] = f16(W[k][n]) ----------------
// Q weights pre-scaled by log2(e): attention scores land in the exp2 domain.
__global__ __launch_bounds__(256) void cvt_wt(const float* __restrict__ wq,
                                              const float* __restrict__ wk,
                                              const float* __restrict__ wv,
                                              _Float16* __restrict__ tq,
                                              _Float16* __restrict__ tk,
                                              _Float16* __restrict__ tv) {
  const float* w = blockIdx.z == 0 ? wq : (blockIdx.z == 1 ? wk : wv);
  _Float16* o = blockIdx.z == 0 ? tq : (blockIdx.z == 1 ? tk : tv);
  float wscale = blockIdx.z == 0 ? 1.4426950408889634f : 1.0f;
  __shared__ float tile[64][65];
  int k0 = blockIdx.x * 64;
  int n0 = blockIdx.y * 64;
  int t = threadIdx.x;
  int tr = t >> 4;
  int tc = (t & 15) * 4;
  for (int i = 0; i < 4; i++) {
    int r = i * 16 + tr;
    float4 val = *(const float4*)(w + (k0 + r) * Dd + n0 + tc);
    tile[r][tc + 0] = val.x; tile[r][tc + 1] = val.y;
    tile[r][tc + 2] = val.z; tile[r][tc + 3] = val.w;
  }
  __syncthreads();
  for (int i = 0; i < 2; i++) {
    int vdx = t + 256 * i;
    int rn = vdx >> 3;
    int c8 = (vdx & 7) * 8;
    union { f16x8 v8; _Float16 h[8]; } o2;
    for (int j = 0; j < 8; j++) o2.h[j] = (_Float16)(tile[c8 + j][rn] * wscale);
    *(f16x8*)(o + (n0 + rn) * Dd + k0 + c8) = o2.v8;
  }
}

// ---------------- K1: projection GEMM (m97 structure) ----------------
// Q,K outputs in [bh][s][dk]; V output written TRANSPOSED [bh][dk][s].
__global__ __launch_bounds__(256) void gemm_qkv(
    const _Float16* __restrict__ xq, const _Float16* __restrict__ xk,
    const _Float16* __restrict__ xv,
    const _Float16* __restrict__ wtq, const _Float16* __restrict__ wtk,
    const _Float16* __restrict__ wtv,
    const float* __restrict__ bq, const float* __restrict__ bk, const float* __restrict__ bv,
    _Float16* __restrict__ oq, _Float16* __restrict__ ok,
    _Float16* __restrict__ ov) {
  int z = blockIdx.z;
  const _Float16* A  = z == 0 ? xq  : (z == 1 ? xk  : xv);
  const _Float16* Bt = z == 0 ? wtq : (z == 1 ? wtk : wtv);
  const float* bias  = z == 0 ? bq  : (z == 1 ? bk  : bv);
  _Float16* out      = z == 0 ? oq  : (z == 1 ? ok  : ov);
  float bscale       = z == 0 ? 1.4426950408889634f : 1.0f;

  __shared__ _Float16 As[128 * 64];
  __shared__ _Float16 Bs[128 * 64];

  int tid = threadIdx.x;
  int w = tid >> 6;
  int l = tid & 63;
  int lr = l & 15, lk = l >> 4;
  int m0 = blockIdx.x * 128;
  int n0 = blockIdx.y * 128;
  int wr = (w >> 1) * 64;
  int wc = (w & 1) * 64;

  f32x4 acc[4][4] = {};

  for (int kt = 0; kt < Dd; kt += 64) {
    __syncthreads();
    for (int i = 0; i < 4; i++) {
      int fbase = i * 256 + w * 64;     // wave-uniform chunk base
      int f = fbase + l;
      int r = f >> 3, c = (f & 7) * 8;
      gload16(A + (m0 + r) * Dd + kt + c, &As[fbase * 8]);
      gload16(Bt + (n0 + r) * Dd + kt + c, &Bs[fbase * 8]);
    }
    __syncthreads();
    for (int kh = 0; kh < 2; kh++) {
      f16x8 af[4], bfr[4];
      for (int mi = 0; mi < 4; mi++)
        af[mi] = *(const f16x8*)&As[(wr + mi * 16 + lr) * 64 + kh * 32 + lk * 8];
      for (int ni = 0; ni < 4; ni++)
        bfr[ni] = *(const f16x8*)&Bs[(wc + ni * 16 + lr) * 64 + kh * 32 + lk * 8];
      for (int mi = 0; mi < 4; mi++)
        for (int ni = 0; ni < 4; ni++)
          acc[mi][ni] = __builtin_amdgcn_mfma_f32_16x16x32_f16(af[mi], bfr[ni], acc[mi][ni], 0, 0, 0);
    }
  }

  if (z == 2) {
    // V^T epilogue: lane holds 4 consecutive s for fixed dk -> one aligned 8B store
    for (int mi = 0; mi < 4; mi++) {
      for (int ni = 0; ni < 4; ni++) {
        int n = n0 + wc + ni * 16 + lr;
        float bval = bias[n];
        int h = n >> 6, dk = n & 63;
        int m = m0 + wr + mi * 16 + lk * 4;
        int b = m >> 11, s = m & 2047;
        f16x4 o4;
        for (int j = 0; j < 4; j++) o4[j] = (_Float16)(acc[mi][ni][j] + bval);
        *(f16x4*)(out + ((size_t)((b * Hh + h) * DK + dk) * Ss + s)) = o4;
      }
    }
  } else {
    for (int mi = 0; mi < 4; mi++) {
      for (int ni = 0; ni < 4; ni++) {
        int n = n0 + wc + ni * 16 + lr;
        float bval = bias[n] * bscale;
        int h = n >> 6, dk = n & 63;
        for (int j = 0; j < 4; j++) {
          int m = m0 + wr + mi * 16 + lk * 4 + j;
          int b = m >> 11, s = m & 2047;
          out[((b * Hh + h) * Ss + s) * DK + dk] = (_Float16)(acc[mi][ni][j] + bval);
        }
      }
    }
  }
}

// ---------------- K3: flash attention, 32x32x16, LDS double-buffered K/V (r7 skeleton) ----------------
// Q,K: [bh][s][64] f16 (Q pre-scaled by log2e); Vt: [bh][64][s] f16; out fp32 = ctx + query.
// 1024 blocks x 4 waves. kv-tile 64 double-buffered via global_load_lds DMA (the only
// staging mechanism this compiler reliably pipelines — r5/6/8/9/10 evidence).
// Softmax: exp2 domain, ONE v_exp_f32 per P (builtin; exp2f libm was the r11 regression).
// lrun lane-partial (epilogue reduce). No setprio (4-wave lockstep = T5-negative regime, m190).
__global__ __launch_bounds__(256) void attn(const _Float16* __restrict__ Qb,
                                            const _Float16* __restrict__ Kb,
                                            const _Float16* __restrict__ Vt,
                                            const float* __restrict__ query,
                                            float* __restrict__ outp) {
  __shared__ _Float16 Kl[2][KVT * 64];
  __shared__ _Float16 Vl[2][KVT * 64];

  int tid = threadIdx.x;
  int w = tid >> 6, l = tid & 63;
  int l31 = l & 31, hi = l >> 5;
  int bh = blockIdx.x;
  int q0 = blockIdx.y * 128 + w * 32;
  const _Float16* Qp = Qb + bh * (Ss * DK);
  const _Float16* Kp = Kb + bh * (Ss * DK);
  const _Float16* Vp = Vt + bh * (DK * Ss);

  // staging: lane l -> row base+(l>>3), LDS slot l&7; global slot = (l&7)^(row&7)
  int srow = l >> 3;
  int sslot = (l & 7) ^ (srow & 7);
  int w16 = w * 16;
  const _Float16* ksrc0 = Kp + (w16 + srow) * DK + sslot * 8;
  const _Float16* ksrc1 = Kp + (w16 + 8 + srow) * DK + sslot * 8;
  const _Float16* vsrc0 = Vp + (w16 + srow) * Ss + sslot * 8;
  const _Float16* vsrc1 = Vp + (w16 + 8 + srow) * Ss + sslot * 8;

#define STAGE(KV0, BUF)                                                   \
  {                                                                       \
    gload16(ksrc0 + (KV0) * DK, &Kl[BUF][w16 * 64]);                      \
    gload16(ksrc1 + (KV0) * DK, &Kl[BUF][(w16 + 8) * 64]);                \
    gload16(vsrc0 + (KV0), &Vl[BUF][w16 * 64]);                           \
    gload16(vsrc1 + (KV0), &Vl[BUF][(w16 + 8) * 64]);                     \
  }

  // Q as B-operand: col=q=q0+l31, k=dk=s*16+hi*8+i
  f16x8 qf[4];
#pragma unroll
  for (int s = 0; s < 4; s++)
    qf[s] = *(const f16x8*)(Qp + (q0 + l31) * DK + s * 16 + hi * 8);

  f32x16 o0 = {}, o1 = {};    // ctx^T: row d=dg*32+(r&3)+8*(r>>2)+4*hi, col q=l31
  float mrun = -1e30f, lrun = 0.f;   // lrun is LANE-PARTIAL (this half's sum)

  // swizzled LDS read slots: slot = ((s*2+hi) ^ (row&7)), row&7 == l31&7 for our reads
  int kv7 = l31 & 7;
  int rslot[4];
#pragma unroll
  for (int s = 0; s < 4; s++) rslot[s] = ((s * 2 + hi) ^ kv7) * 8;

  STAGE(0, 0)
  __syncthreads();

  int cur = 0;
  for (int kv0 = 0; kv0 < Ss; kv0 += KVT) {
    // issue next-tile staging (DMA completes under this tile's compute)
    if (kv0 + KVT < Ss) STAGE(kv0 + KVT, cur ^ 1)

    // ---- QK^T (swapped): A=K rows kv from LDS, B=qf ----
    const _Float16* Kc = &Kl[cur][0];
    f32x16 s0 = {}, s1 = {};
#pragma unroll
    for (int s = 0; s < 4; s++) {
      f16x8 ka = *(const f16x8*)&Kc[l31 * 64 + rslot[s]];
      s0 = __builtin_amdgcn_mfma_f32_32x32x16_f16(ka, qf[s], s0, 0, 0, 0);
    }
#pragma unroll
    for (int s = 0; s < 4; s++) {
      f16x8 kb = *(const f16x8*)&Kc[(32 + l31) * 64 + rslot[s]];
      s1 = __builtin_amdgcn_mfma_f32_32x32x16_f16(kb, qf[s], s1, 0, 0, 0);
    }

    // ---- lane-local online softmax (exp2 domain, 1 v_exp per P) ----
    float m8[8];
#pragma unroll
    for (int r = 0; r < 8; r++)
      m8[r] = fmaxf(fmaxf(s0[r], s0[r + 8]), fmaxf(s1[r], s1[r + 8]));  // v_max3-fusable
#pragma unroll
    for (int d = 4; d >= 1; d >>= 1)
#pragma unroll
      for (int r = 0; r < 4; r++) if (r < d) m8[r] = fmaxf(m8[r], m8[r + d]);
    float pm = fmaxf(m8[0], __shfl_xor(m8[0], 32));

    if (!__all(pm - mrun <= 8.f)) {        // defer-max (T13), log2 units: P <= 2^8
      float mn = fmaxf(mrun, pm);
      float sc_ = ex2(mrun - mn);
      mrun = mn;
      lrun *= sc_;
#pragma unroll
      for (int r = 0; r < 16; r++) { o0[r] *= sc_; o1[r] *= sc_; }
    }
#pragma unroll
    for (int r = 0; r < 16; r++) {
      s0[r] = ex2(s0[r] - mrun);
      s1[r] = ex2(s1[r] - mrun);
    }
    float s8[8];
#pragma unroll
    for (int r = 0; r < 8; r++) s8[r] = (s0[r] + s0[r + 8]) + (s1[r] + s1[r + 8]);
#pragma unroll
    for (int d = 4; d >= 1; d >>= 1)
#pragma unroll
      for (int r = 0; r < 4; r++) if (r < d) s8[r] += s8[r + d];
    lrun += s8[0];    // lane-partial; cross-half reduce deferred to epilogue

    // ---- pack P + permlane32_swap + PV MFMA (V from LDS, swizzled) ----
    const _Float16* Vc = &Vl[cur][0];
#define PVSTEP(SRC, OFF, KST)                                                   \
    {                                                                           \
      unsigned a0 = pk2u(SRC[(OFF) + 0], SRC[(OFF) + 1]);                       \
      unsigned a1 = pk2u(SRC[(OFF) + 2], SRC[(OFF) + 3]);                       \
      unsigned b0 = pk2u(SRC[(OFF) + 4], SRC[(OFF) + 5]);                       \
      unsigned b1 = pk2u(SRC[(OFF) + 6], SRC[(OFF) + 7]);                       \
      uint2v r0 = __builtin_amdgcn_permlane32_swap(a0, b0, false, false);       \
      uint2v r1 = __builtin_amdgcn_permlane32_swap(a1, b1, false, false);       \
      union { unsigned u[4]; f16x8 v; } pf;                                     \
      pf.u[0] = r0[0]; pf.u[1] = r1[0]; pf.u[2] = r0[1]; pf.u[3] = r1[1];       \
      f16x8 v0 = *(const f16x8*)&Vc[l31 * 64 + rslot[KST]];                     \
      f16x8 v1 = *(const f16x8*)&Vc[(32 + l31) * 64 + rslot[KST]];              \
      o0 = __builtin_amdgcn_mfma_f32_32x32x16_f16(v0, pf.v, o0, 0, 0, 0);       \
      o1 = __builtin_amdgcn_mfma_f32_32x32x16_f16(v1, pf.v, o1, 0, 0, 0);       \
    }
    PVSTEP(s0, 0, 0)
    PVSTEP(s0, 8, 1)
    PVSTEP(s1, 0, 2)
    PVSTEP(s1, 8, 3)
#undef PVSTEP

    __syncthreads();   // reads of buf[cur] done; staging of buf[cur^1] drained
    cur ^= 1;
  }

  // ---- epilogue: reduce lane-partial lrun, normalize, add residual ----
  lrun += __shfl_xor(lrun, 32);
  int b = bh >> 4, h = bh & 15;
  float inv = 1.f / lrun;
  int base = (b * Ss + q0 + l31) * Dd + h * 64;
#pragma unroll
  for (int rq = 0; rq < 4; rq++) {
    int d0 = rq * 8 + hi * 4;
    float4 qv0 = *(const float4*)(query + base + d0);
    float4 ov0;
    ov0.x = o0[rq * 4 + 0] * inv + qv0.x;
    ov0.y = o0[rq * 4 + 1] * inv + qv0.y;
    ov0.z = o0[rq * 4 + 2] * inv + qv0.z;
    ov0.w = o0[rq * 4 + 3] * inv + qv0.w;
    *(float4*)(outp + base + d0) = ov0;
    float4 qv1 = *(const float4*)(query + base + 32 + d0);
    float4 ov1;
    ov1.x = o1[rq * 4 + 0] * inv + qv1.x;
    ov1.y = o1[rq * 4 + 1] * inv + qv1.y;
    ov1.z = o1[rq * 4 + 2] * inv + qv1.z;
    ov1.w = o1[rq * 4 + 3] * inv + qv1.w;
    *(float4*)(outp + base + 32 + d0) = ov1;
  }
#undef STAGE
}

extern "C" void kernel_launch(void* const* d_in, const int* in_sizes, int n_in,
                              void* d_out, int out_size, void* d_ws, size_t ws_size,
                              hipStream_t stream) {
  const float* query = (const float*)d_in[0];
  const float* key   = (const float*)d_in[1];
  const float* value = (const float*)d_in[2];
  const float* Wq = (const float*)d_in[3];
  const float* bq = (const float*)d_in[4];
  const float* Wk = (const float*)d_in[5];
  const float* bk = (const float*)d_in[6];
  const float* Wv = (const float*)d_in[7];
  const float* bv = (const float*)d_in[8];
  float* out = (float*)d_out;

  _Float16* ws = (_Float16*)d_ws;
  const size_t ACT = (size_t)Mm * Dd;
  const size_t WSZ = (size_t)Dd * Dd;
  _Float16* Xq   = ws;
  _Float16* Xk   = Xq + ACT;
  _Float16* Xv   = Xk + ACT;
  _Float16* Wtq  = Xv + ACT;
  _Float16* Wtk  = Wtq + WSZ;
  _Float16* Wtv  = Wtk + WSZ;
  _Float16* Qb   = Wtv + WSZ;
  _Float16* Kb   = Qb + ACT;
  _Float16* VtT  = Kb + ACT;   // gemm writes V^T [bh][dk][s] here directly

  cvt_act<<<dim3(4096, 1, 3), dim3(256), 0, stream>>>(query, key, value, Xq, Xk, Xv);
  cvt_wt<<<dim3(16, 16, 3), dim3(256), 0, stream>>>(Wq, Wk, Wv, Wtq, Wtk, Wtv);
  gemm_qkv<<<dim3(64, 8, 3), dim3(256), 0, stream>>>(Xq, Xk, Xv, Wtq, Wtk, Wtv,
                                                     bq, bk, bv, Qb, Kb, VtT);
  attn<<<dim3(64, 16), dim3(256), 0, stream>>>(Qb, Kb, VtT, query, out);
}